// Round 3
// baseline (30.958 us; speedup 1.0000x reference)
//
#include <hip/hip_runtime.h>
#include <math.h>

#define HEADS 4
#define CDIM 128
#define HDIM 512   // HEADS*CDIM
#define FEAT 128
#define CAPSLOTS 1024

// ---------------- Kernel 0: zero the two counters ----------------
__global__ void zero_kernel(int* __restrict__ p) {
    if (threadIdx.x < 2) p[threadIdx.x] = 0;   // p[0]=count, p[1]=done
}

// ---------------- Kernel A: find edges with dst == target (int4) ----------------
__global__ void scan_edges_kernel(const int* __restrict__ ei, int E,
                                  const int* __restrict__ tgt_p,
                                  int* __restrict__ count,
                                  int* __restrict__ srcList, int cap) {
    int tgt = *tgt_p;
    int g = blockIdx.x * blockDim.x + threadIdx.x;
    int base = g * 4;
    if (base + 3 < E) {
        int4 d = *(const int4*)(ei + E + base);
        if (d.x == tgt) { int p = atomicAdd(count, 1); if (p < cap) srcList[p] = ei[base + 0]; }
        if (d.y == tgt) { int p = atomicAdd(count, 1); if (p < cap) srcList[p] = ei[base + 1]; }
        if (d.z == tgt) { int p = atomicAdd(count, 1); if (p < cap) srcList[p] = ei[base + 2]; }
        if (d.w == tgt) { int p = atomicAdd(count, 1); if (p < cap) srcList[p] = ei[base + 3]; }
    } else {
        for (int k = base; k < E; ++k)
            if (ei[E + k] == tgt) { int p = atomicAdd(count, 1); if (p < cap) srcList[p] = ei[k]; }
    }
}

// ---------------- Kernel B: fused feat -> h -> logits -> (last block) finalize ----------------
__global__ void fused_kernel(const float* __restrict__ des, const float* __restrict__ tw,
                             const float* __restrict__ npr, const float* __restrict__ cpr,
                             const float* __restrict__ Wd, const float* __restrict__ bd,
                             const float* __restrict__ Wt, const float* __restrict__ bt,
                             const float* __restrict__ Wn, const float* __restrict__ bn,
                             const float* __restrict__ Wc, const float* __restrict__ bc,
                             const float* __restrict__ Wg,
                             const float* __restrict__ att_src, const float* __restrict__ att_dst,
                             const float* __restrict__ x, const float* __restrict__ bgat,
                             const float* __restrict__ Wo1, const float* __restrict__ bo1,
                             const float* __restrict__ Wo2, const float* __restrict__ bo2,
                             const int* __restrict__ tgt_p, int* __restrict__ counters, int cap,
                             const int* __restrict__ srcList,
                             float* __restrict__ aS, float* __restrict__ aD,
                             float* __restrict__ h_all,
                             float* __restrict__ out) {
    __shared__ float sdes[768];
    __shared__ float stw[768];
    __shared__ float snp8[8];
    __shared__ float sfeat[FEAT];
    __shared__ float part[256];
    __shared__ float pr[HDIM];       // reused as sout in finalize
    __shared__ float scomb[144];
    __shared__ float shmid[64];
    __shared__ int sIsLast;

    const int* count = counters;
    int* done = counters + 1;

    int cnt = min(*count, cap);
    int tid = threadIdx.x;           // blockDim = 256
    int j = tid & 31, chk = tid >> 5;
    int wv = tid >> 6, lane = tid & 63;

    for (int slot = blockIdx.x; slot <= cnt; slot += gridDim.x) {
        int node = (slot == cnt) ? *tgt_p : srcList[slot];

        // ---- stage node row ----
        if (tid < 192) {
            ((float4*)sdes)[tid] = ((const float4*)(des + (size_t)node * 768))[tid];
            ((float4*)stw)[tid]  = ((const float4*)(tw  + (size_t)node * 768))[tid];
        } else if (tid < 197) {
            snp8[tid - 192] = npr[node * 5 + (tid - 192)];
        } else if (tid == 197) {
            snp8[5] = cpr[node];
        }
        __syncthreads();

        // ---- feature: des @ Wd (8x32 split) ----
        {
            float p = 0.f;
            const float* w = Wd + (size_t)(chk * 96) * 32 + j;
            const float* s = sdes + chk * 96;
            #pragma unroll 8
            for (int k = 0; k < 96; ++k) p = fmaf(s[k], w[(size_t)k * 32], p);
            part[tid] = p;
        }
        __syncthreads();
        if (tid < 32) {
            float a = bd[tid];
            #pragma unroll
            for (int c = 0; c < 8; ++c) a += part[c * 32 + tid];
            sfeat[tid] = a > 0.f ? a : 0.01f * a;
        }
        __syncthreads();
        // ---- tweet @ Wt ----
        {
            float p = 0.f;
            const float* w = Wt + (size_t)(chk * 96) * 32 + j;
            const float* s = stw + chk * 96;
            #pragma unroll 8
            for (int k = 0; k < 96; ++k) p = fmaf(s[k], w[(size_t)k * 32], p);
            part[tid] = p;
        }
        __syncthreads();
        if (tid < 32) {
            float a = bt[tid];
            #pragma unroll
            for (int c = 0; c < 8; ++c) a += part[c * 32 + tid];
            sfeat[32 + tid] = a > 0.f ? a : 0.01f * a;
        } else if (tid < 64) {
            int jj = tid - 32;
            float a = bn[jj];
            #pragma unroll
            for (int k = 0; k < 5; ++k) a = fmaf(snp8[k], Wn[k * 32 + jj], a);
            sfeat[64 + jj] = a > 0.f ? a : 0.01f * a;
        } else if (tid < 96) {
            int jj = tid - 64;
            float a = fmaf(snp8[5], Wc[jj], bc[jj]);
            sfeat[96 + jj] = a > 0.f ? a : 0.01f * a;
        }
        __syncthreads();

        // ---- h = feat @ Wg : 2 outputs / thread, coalesced Wg columns ----
        float hv0 = 0.f, hv1 = 0.f;
        {
            const float* w0 = Wg + tid;
            const float* w1 = Wg + 256 + tid;
            #pragma unroll 16
            for (int k = 0; k < FEAT; ++k) {
                float f = sfeat[k];
                hv0 = fmaf(f, w0[(size_t)k * HDIM], hv0);
                hv1 = fmaf(f, w1[(size_t)k * HDIM], hv1);
            }
            h_all[(size_t)slot * HDIM + tid]       = hv0;
            h_all[(size_t)slot * HDIM + 256 + tid] = hv1;
            pr[tid]       = hv0 * att_src[tid];
            pr[256 + tid] = hv1 * att_src[256 + tid];
        }
        __syncthreads();
        // per-head reduce: wave wv reduces head wv (128 values)
        {
            float v = pr[wv * 128 + lane] + pr[wv * 128 + 64 + lane];
            #pragma unroll
            for (int off = 32; off > 0; off >>= 1) v += __shfl_down(v, off);
            if (lane == 0) aS[slot * HEADS + wv] = v;
        }
        if (slot == cnt) {
            __syncthreads();
            pr[tid]       = hv0 * att_dst[tid];
            pr[256 + tid] = hv1 * att_dst[256 + tid];
            __syncthreads();
            float v = pr[wv * 128 + lane] + pr[wv * 128 + 64 + lane];
            #pragma unroll
            for (int off = 32; off > 0; off >>= 1) v += __shfl_down(v, off);
            if (lane == 0) aD[wv] = v;
        }
        __syncthreads();   // protect LDS before next slot
    }

    // ---- last-block handoff ----
    if (tid == 0) {
        __threadfence();                       // release: WB dirty L2 (agent scope)
        int old = atomicAdd(done, 1);
        sIsLast = (old == (int)gridDim.x - 1);
    }
    __syncthreads();
    if (!sIsLast) return;
    __threadfence();                           // acquire: INV stale L1/L2

    // ---- finalize on the last block (256 threads) ----
    int M = cnt + 1;
    #pragma unroll
    for (int rep = 0; rep < 2; ++rep) {
        int o = tid + rep * 256;
        int hd = o >> 7;
        float adv = aD[hd];
        float m = -INFINITY;
        for (int s = 0; s < M; ++s) {
            float e = aS[s * HEADS + hd] + adv;
            e = e > 0.f ? e : 0.2f * e;        // leaky_relu slope 0.2
            m = fmaxf(m, e);
        }
        float denom = 0.f, acc = 0.f;
        for (int s = 0; s < M; ++s) {
            float e = aS[s * HEADS + hd] + adv;
            e = e > 0.f ? e : 0.2f * e;
            float ex = expf(e - m);
            denom += ex;
            acc = fmaf(ex, h_all[(size_t)s * HDIM + o], acc);
        }
        pr[o] = acc / denom;
    }
    __syncthreads();

    if (tid < 128) {
        scomb[tid] = (pr[tid] + pr[128 + tid] + pr[256 + tid] + pr[384 + tid]) * 0.25f
                     + bgat[tid];
    } else if (tid < 136) {
        scomb[tid] = x[tid - 128];
    }
    __syncthreads();

    if (tid < 64) {
        float a = bo1[tid];
        #pragma unroll 8
        for (int k = 0; k < 136; ++k) a = fmaf(scomb[k], Wo1[k * 64 + tid], a);
        shmid[tid] = a > 0.f ? a : 0.f;
    }
    __syncthreads();
    if (tid < 5) {
        float a = bo2[tid];
        #pragma unroll 8
        for (int k = 0; k < 64; ++k) a = fmaf(shmid[k], Wo2[k * 5 + tid], a);
        out[tid] = a;
    }
}

extern "C" void kernel_launch(void* const* d_in, const int* in_sizes, int n_in,
                              void* d_out, int out_size, void* d_ws, size_t ws_size,
                              hipStream_t stream) {
    const float* x    = (const float*)d_in[0];
    const float* des  = (const float*)d_in[1];
    const float* tw   = (const float*)d_in[2];
    const float* npr  = (const float*)d_in[3];
    const float* cpr  = (const float*)d_in[4];
    const int*   ei   = (const int*)d_in[5];     // [2, E] flat
    const int*   tgt  = (const int*)d_in[6];
    const float* Wd   = (const float*)d_in[7];   const float* bd  = (const float*)d_in[8];
    const float* Wt   = (const float*)d_in[9];   const float* bt  = (const float*)d_in[10];
    const float* Wn   = (const float*)d_in[11];  const float* bn  = (const float*)d_in[12];
    const float* Wc   = (const float*)d_in[13];  const float* bc  = (const float*)d_in[14];
    const float* Wg   = (const float*)d_in[15];
    const float* as_  = (const float*)d_in[16];  const float* ad_ = (const float*)d_in[17];
    const float* bg   = (const float*)d_in[18];
    const float* Wo1  = (const float*)d_in[19];  const float* bo1 = (const float*)d_in[20];
    const float* Wo2  = (const float*)d_in[21];  const float* bo2 = (const float*)d_in[22];

    const int E = in_sizes[5] / 2;

    // ws layout: [0]=count,[4]=done | 512: srcList[cap] | aS[(cap+1)*4] | aD[4] | h_all[(cap+1)*512]
    const long long per = 4 + 16 + HDIM * 4;   // bytes per slot
    long long avail = ((long long)ws_size - 8192) / per - 2;
    int cap = CAPSLOTS;
    if (avail < cap) cap = (int)avail;
    if (cap < 1) cap = 1;

    char* ws = (char*)d_ws;
    int*   counters = (int*)ws;
    int*   srcList  = (int*)(ws + 512);
    float* aS       = (float*)(ws + 512 + (size_t)cap * 4);
    float* aD       = aS + (size_t)(cap + 1) * HEADS;
    float* h_all    = aD + 8;

    zero_kernel<<<1, 64, 0, stream>>>(counters);

    int nquad = (E + 3) / 4;
    scan_edges_kernel<<<(nquad + 255) / 256, 256, 0, stream>>>(ei, E, tgt, counters, srcList, cap);

    fused_kernel<<<16, 256, 0, stream>>>(des, tw, npr, cpr,
                                         Wd, bd, Wt, bt, Wn, bn, Wc, bc,
                                         Wg, as_, ad_,
                                         x, bg, Wo1, bo1, Wo2, bo2,
                                         tgt, counters, cap, srcList,
                                         aS, aD, h_all, (float*)d_out);
}